// Round 7
// baseline (789.481 us; speedup 1.0000x reference)
//
#include <hip/hip_runtime.h>

// LSTM: B=256, T=512, I=256, H=128 (4H=512 gates), then MLP 128->64->32->4.
//   gemm_gx_kernel : bf16 MFMA GEMM (double-buffered LDS), gx stored bf16 in a
//       UNIT-PACKED layout: idx(t,batch,gate) = (((t*64+blk)*8+w)*64+L)*4+g where
//       blk=batch>>2, j=gate&127, w=j>>4, L=(j&15)*4+(batch&3), g=gate>>7.
//       -> recurrence lane L loads its unit's 4 gates as ONE 8-B load.
//   lstm_mfma_kernel : 64 blocks (RB=4) x 512 thr (8 waves). W_hh static in VGPRs.
//       ROUND 7: lane-spread activations. After the 16 MFMAs, lanes n<4 write real
//       D cols to a wave-private LDS exchange buffer; ALL 64 lanes then each
//       process exactly one (j,b) unit: 5 transcendental units/lane instead of 20
//       (75% of activation VALU was garbage-lane work). c lives in-lane per unit.
//   head_kernel : tiny MLP per row.

#define TC       128
#define NCHUNK   4
#define BATCH    256
#define TSEQ     512
#define ISZ      256
#define HSZ      128
#define G4       512
#define RB       4
#define NBLK     (BATCH / RB)
#define HROW     136              // LDS h row stride in shorts (272 B)
#define GX_PER_T 131072           // gx elements per timestep
#define PF       4                // gx prefetch depth in steps

typedef __attribute__((ext_vector_type(8))) short short8;
typedef __attribute__((ext_vector_type(4))) short shortx4;
typedef __attribute__((ext_vector_type(4))) float f32x4;

__device__ __forceinline__ void barrier_nodrain() {
    // s_barrier WITHOUT the compiler's vmcnt(0) drain: LDS consistency only.
    __asm__ __volatile__("s_waitcnt lgkmcnt(0)\n\ts_barrier" ::: "memory");
}
__device__ __forceinline__ void lds_fence() {
    // order this wave's LDS write->read (exchange buffer is wave-private)
    __asm__ __volatile__("s_waitcnt lgkmcnt(0)" ::: "memory");
}

__device__ __forceinline__ float fast_rcp(float x) {
    return __builtin_amdgcn_rcpf(x);
}
__device__ __forceinline__ float sigmoidf_(float x) {
    return fast_rcp(1.0f + __expf(-x));
}
__device__ __forceinline__ float tanhf_(float x) {
    float e = __expf(2.0f * x);               // inf-safe
    return 1.0f - 2.0f * fast_rcp(e + 1.0f);
}
__device__ __forceinline__ unsigned short f2bf(float x) {  // fp32 -> bf16 RNE
    union { float f; unsigned u; } v; v.f = x;
    unsigned r = v.u + 0x7fffu + ((v.u >> 16) & 1u);
    return (unsigned short)(r >> 16);
}
__device__ __forceinline__ float bf2f(short b) {
    union { unsigned u; float f; } v;
    v.u = ((unsigned)(unsigned short)b) << 16;
    return v.f;
}
__device__ __forceinline__ unsigned packbf(float lo, float hi) {
    return ((unsigned)f2bf(hi) << 16) | (unsigned)f2bf(lo);
}

// ---------------------------------------------------------------------------
// bf16 MFMA GEMM: per chunk M = TC*256 (m=(tl,batch)), N = 512 gates, K = 256.
// Double-buffered LDS: stage slice ks+1 while computing slice ks; 1 barrier/slice.
__global__ __launch_bounds__(256, 2) void gemm_gx_kernel(
    const float* __restrict__ x, const float* __restrict__ Wih,
    const float* __restrict__ bih, const float* __restrict__ bhh,
    unsigned short* __restrict__ gxb, int t0)
{
    __shared__ __align__(16) short As[2][128 * 32];
    __shared__ __align__(16) short Bs[2][128 * 32];
    const int tid = threadIdx.x;
    const int mt  = blockIdx.x;
    const int nt  = blockIdx.y;
    const int tl  = mt >> 1;
    const int b0  = (mt & 1) * 128;
    const int n0  = nt * 128;

    const int w    = tid >> 6;
    const int lane = tid & 63;
    const int n    = lane & 15;
    const int quad = lane >> 4;
    const int mq   = w & 1;
    const int nq   = w >> 1;

    const int srow = tid >> 1;
    const int skh  = (tid & 1) * 16;
    const float* xrow = x + ((size_t)(b0 + srow) * TSEQ + (size_t)(t0 + tl)) * ISZ + skh;
    const float* wrow = Wih + (size_t)(n0 + srow) * ISZ + skh;

    f32x4 acc[4][4];
#pragma unroll
    for (int mi = 0; mi < 4; ++mi)
#pragma unroll
        for (int ni = 0; ni < 4; ++ni)
            acc[mi][ni] = (f32x4){0.f, 0.f, 0.f, 0.f};

    {
        float4 pa[4], pb[4];
#pragma unroll
        for (int j = 0; j < 4; ++j) {
            pa[j] = *(const float4*)(xrow + j * 4);
            pb[j] = *(const float4*)(wrow + j * 4);
        }
        unsigned ua[8], ub[8];
#pragma unroll
        for (int j = 0; j < 4; ++j) {
            ua[2 * j]     = packbf(pa[j].x, pa[j].y);
            ua[2 * j + 1] = packbf(pa[j].z, pa[j].w);
            ub[2 * j]     = packbf(pb[j].x, pb[j].y);
            ub[2 * j + 1] = packbf(pb[j].z, pb[j].w);
        }
        *(uint4*)(&As[0][srow * 32 + skh])     = (uint4){ua[0], ua[1], ua[2], ua[3]};
        *(uint4*)(&As[0][srow * 32 + skh + 8]) = (uint4){ua[4], ua[5], ua[6], ua[7]};
        *(uint4*)(&Bs[0][srow * 32 + skh])     = (uint4){ub[0], ub[1], ub[2], ub[3]};
        *(uint4*)(&Bs[0][srow * 32 + skh + 8]) = (uint4){ub[4], ub[5], ub[6], ub[7]};
    }
    barrier_nodrain();

    for (int ks = 0; ks < 8; ++ks) {
        const int cur = ks & 1;
        const int nxt = cur ^ 1;

        float4 pa[4], pb[4];
        if (ks < 7) {
#pragma unroll
            for (int j = 0; j < 4; ++j) {
                pa[j] = *(const float4*)(xrow + (ks + 1) * 32 + j * 4);
                pb[j] = *(const float4*)(wrow + (ks + 1) * 32 + j * 4);
            }
        }

        short8 af[4], bf[4];
#pragma unroll
        for (int mi = 0; mi < 4; ++mi)
            af[mi] = *(const short8*)(&As[cur][((mq * 4 + mi) * 16 + n) * 32 + quad * 8]);
#pragma unroll
        for (int ni = 0; ni < 4; ++ni)
            bf[ni] = *(const short8*)(&Bs[cur][((nq * 4 + ni) * 16 + n) * 32 + quad * 8]);
#pragma unroll
        for (int mi = 0; mi < 4; ++mi)
#pragma unroll
            for (int ni = 0; ni < 4; ++ni)
                acc[mi][ni] = __builtin_amdgcn_mfma_f32_16x16x32_bf16(
                    af[mi], bf[ni], acc[mi][ni], 0, 0, 0);

        if (ks < 7) {
            unsigned ua[8], ub[8];
#pragma unroll
            for (int j = 0; j < 4; ++j) {
                ua[2 * j]     = packbf(pa[j].x, pa[j].y);
                ua[2 * j + 1] = packbf(pa[j].z, pa[j].w);
                ub[2 * j]     = packbf(pb[j].x, pb[j].y);
                ub[2 * j + 1] = packbf(pb[j].z, pb[j].w);
            }
            *(uint4*)(&As[nxt][srow * 32 + skh])     = (uint4){ua[0], ua[1], ua[2], ua[3]};
            *(uint4*)(&As[nxt][srow * 32 + skh + 8]) = (uint4){ua[4], ua[5], ua[6], ua[7]};
            *(uint4*)(&Bs[nxt][srow * 32 + skh])     = (uint4){ub[0], ub[1], ub[2], ub[3]};
            *(uint4*)(&Bs[nxt][srow * 32 + skh + 8]) = (uint4){ub[4], ub[5], ub[6], ub[7]};
        }
        barrier_nodrain();
    }

    // epilogue: bias + bf16, UNIT-PACKED scatter
#pragma unroll
    for (int ni = 0; ni < 4; ++ni) {
        const int gate = n0 + nq * 64 + ni * 16 + n;
        const float bias = bih[gate] + bhh[gate];
        const int g   = gate >> 7;
        const int jj  = gate & 127;
        const int ww  = jj >> 4;
        const int jl2 = jj & 15;
#pragma unroll
        for (int mi = 0; mi < 4; ++mi) {
            const int bb   = b0 + mq * 64 + mi * 16 + quad * 4;  // batch base, mult of 4
            const int blk2 = bb >> 2;
            const size_t base =
                ((((size_t)tl * 64 + blk2) * 8 + ww) * 64 + (size_t)(jl2 * 4)) * 4 + g;
#pragma unroll
            for (int r = 0; r < 4; ++r)                          // r = batch&3 -> L+r
                gxb[base + (size_t)r * 4] = f2bf(acc[mi][ni][r] + bias);
        }
    }
}

// ---------------------------------------------------------------------------
// MFMA recurrence, lane-spread activations.
// 64 blocks x 512 thr (8 waves), RB=4 batch rows per block.
// Wave w computes gate-tiles {w,8+w,16+w,24+w}: j in [16w,16w+16), D cols 0..3 real.
// Unit mapping: lane L -> (j = 16w + (L>>2), b = L&3); c held in-lane.
__global__ __launch_bounds__(512, 2) void lstm_mfma_kernel(
    const unsigned short* __restrict__ gxb, const float* __restrict__ Whh,
    float* __restrict__ hc, int first)
{
    __shared__ __align__(16) short h_lds[2 * RB * HROW];   // double-buffered h (bf16)
    __shared__ __align__(16) float ex_lds[8 * 256];        // per-wave exchange: [g][b][j]
    const int blk  = blockIdx.x;
    const int b0   = blk * RB;
    const int tid  = threadIdx.x;
    const int w    = tid >> 6;
    const int lane = tid & 63;
    const int n    = lane & 15;
    const int quad = lane >> 4;
    const int nb   = lane & 3;           // B-frag col (clamped) == unit batch bu
    const int jl   = lane >> 2;          // unit j-local 0..15
    const int j    = 16 * w + jl;        // unit hidden index
    float* exw = ex_lds + w * 256;

    // static A-frags: W_hh[128g + 16w + n][32ks + 8quad + i] as bf16
    short8 Af[4][4];
#pragma unroll
    for (int g = 0; g < 4; ++g) {
        const float* row = Whh + (size_t)(128 * g + 16 * w + n) * HSZ + 8 * quad;
#pragma unroll
        for (int ks = 0; ks < 4; ++ks)
#pragma unroll
            for (int i = 0; i < 8; ++i)
                Af[g][ks][i] = (short)f2bf(row[32 * ks + i]);
    }

    // init unit state: every thread owns one (j, b) unit
    float c1 = 0.f, hl1 = 0.f;
    {
        unsigned short h0 = 0;
        if (!first) {
            c1 = hc[(size_t)BATCH * HSZ + (size_t)(b0 + nb) * HSZ + j];
            h0 = f2bf(hc[(size_t)(b0 + nb) * HSZ + j]);
        }
        *(unsigned short*)&h_lds[nb * HROW + j] = h0;   // buffer 0
    }

    // gx: one 8-B load per lane per step (unit-packed layout)
    const unsigned short* gp = gxb + (size_t)(((blk * 8 + w) * 64 + lane) * 4);
    shortx4 gq[PF];
#pragma unroll
    for (int d = 0; d < PF; ++d)
        gq[d] = *(const shortx4*)(gp + (size_t)d * GX_PER_T);

    barrier_nodrain();

    for (int t = 0; t < TC; t += PF) {
#pragma unroll
        for (int u = 0; u < PF; ++u) {
            const int tt = t + u;
            const short* hb_r = h_lds + (u & 1) * (RB * HROW);
            short*       hb_w = h_lds + ((u & 1) ^ 1) * (RB * HROW);

            short8 Bf[4];
#pragma unroll
            for (int ks = 0; ks < 4; ++ks)
                Bf[ks] = *(const short8*)(&hb_r[nb * HROW + 32 * ks + 8 * quad]);

            // refill prefetch slot u for step tt+PF
            {
                const int tf = (tt + PF < TC) ? (tt + PF) : (TC - 1);
                shortx4 gnew = *(const shortx4*)(gp + (size_t)tf * GX_PER_T);
                // MFMAs: zero-C first, 4 independent chains
                f32x4 acc[4];
#pragma unroll
                for (int g = 0; g < 4; ++g)
                    acc[g] = __builtin_amdgcn_mfma_f32_16x16x32_bf16(
                        Af[g][0], Bf[0], (f32x4){0.f, 0.f, 0.f, 0.f}, 0, 0, 0);
#pragma unroll
                for (int ks = 1; ks < 4; ++ks)
#pragma unroll
                    for (int g = 0; g < 4; ++g)
                        acc[g] = __builtin_amdgcn_mfma_f32_16x16x32_bf16(
                            Af[g][ks], Bf[ks], acc[g], 0, 0, 0);

                // exchange: real cols (n<4) -> wave-private LDS, [g][b][j] fp32
                if (n < 4) {
#pragma unroll
                    for (int g = 0; g < 4; ++g)
                        *(f32x4*)(&exw[(g * 4 + n) * 16 + 4 * quad]) = acc[g];
                }
                lds_fence();   // wave-internal write->read ordering

                const float d0 = exw[(0 * 4 + nb) * 16 + jl];
                const float d1 = exw[(1 * 4 + nb) * 16 + jl];
                const float d2 = exw[(2 * 4 + nb) * 16 + jl];
                const float d3 = exw[(3 * 4 + nb) * 16 + jl];

                const float ig = sigmoidf_(d0 + bf2f(gq[u][0]));
                const float fg = sigmoidf_(d1 + bf2f(gq[u][1]));
                const float gg = tanhf_(d2 + bf2f(gq[u][2]));
                const float og = sigmoidf_(d3 + bf2f(gq[u][3]));
                c1  = fg * c1 + ig * gg;
                hl1 = og * tanhf_(c1);
                gq[u] = gnew;
            }
            *(unsigned short*)&hb_w[nb * HROW + j] = f2bf(hl1);
            barrier_nodrain();
        }
    }

    hc[(size_t)(b0 + nb) * HSZ + j] = hl1;
    hc[(size_t)BATCH * HSZ + (size_t)(b0 + nb) * HSZ + j] = c1;
}

// ---------------------------------------------------------------------------
// MLP head: one block (64 threads) per batch row.
__global__ __launch_bounds__(64) void head_kernel(
    const float* __restrict__ hc,
    const float* __restrict__ W1, const float* __restrict__ b1,
    const float* __restrict__ W2, const float* __restrict__ b2,
    const float* __restrict__ W3, const float* __restrict__ b3,
    float* __restrict__ out)
{
    __shared__ float hs[HSZ];
    __shared__ float o1[64];
    __shared__ float o2[32];
    const int bidx = blockIdx.x;
    const int t = threadIdx.x;
    hs[t]      = hc[bidx * HSZ + t];
    hs[t + 64] = hc[bidx * HSZ + t + 64];
    __syncthreads();
    {
        float a = b1[t];
#pragma unroll 8
        for (int k = 0; k < HSZ; ++k) a += W1[t * HSZ + k] * hs[k];
        o1[t] = fmaxf(a, 0.0f);
    }
    __syncthreads();
    if (t < 32) {
        float a = b2[t];
#pragma unroll 8
        for (int k = 0; k < 64; ++k) a += W2[t * 64 + k] * o1[k];
        o2[t] = fmaxf(a, 0.0f);
    }
    __syncthreads();
    if (t < 4) {
        float a = b3[t];
#pragma unroll
        for (int k = 0; k < 32; ++k) a += W3[t * 32 + k] * o2[k];
        out[bidx * 4 + t] = a;
    }
}

// ---------------------------------------------------------------------------
extern "C" void kernel_launch(void* const* d_in, const int* in_sizes, int n_in,
                              void* d_out, int out_size, void* d_ws, size_t ws_size,
                              hipStream_t stream) {
    const float* x   = (const float*)d_in[0];
    const float* Wih = (const float*)d_in[1];
    const float* Whh = (const float*)d_in[2];
    const float* bih = (const float*)d_in[3];
    const float* bhh = (const float*)d_in[4];
    const float* W1  = (const float*)d_in[5];
    const float* b1  = (const float*)d_in[6];
    const float* W2  = (const float*)d_in[7];
    const float* b2  = (const float*)d_in[8];
    const float* W3  = (const float*)d_in[9];
    const float* b3  = (const float*)d_in[10];
    float* out = (float*)d_out;

    unsigned short* gxb = (unsigned short*)d_ws;                   // 33.55 MB bf16
    float* hc = (float*)((char*)d_ws + (size_t)TC * GX_PER_T * 2); // 256 KB h+c

    for (int c = 0; c < NCHUNK; ++c) {
        gemm_gx_kernel<<<dim3(2 * TC, 4), 256, 0, stream>>>(x, Wih, bih, bhh, gxb, c * TC);
        lstm_mfma_kernel<<<dim3(NBLK), 512, 0, stream>>>(gxb, Whh, hc, c == 0);
    }
    head_kernel<<<dim3(BATCH), 64, 0, stream>>>(hc, W1, b1, W2, b2, W3, b3, out);
}

// Round 8
// 649.241 us; speedup vs baseline: 1.2160x; 1.2160x over previous
//
#include <hip/hip_runtime.h>
#include <hip/hip_bf16.h>

// LSTM: B=256, T=512, I=256, H=128 (4H=512 gates), then MLP 128->64->32->4.
//   gemm_gx_kernel : bf16 MFMA GEMM (double-buffered LDS).
//       ROUND 8: gx stored bf16 in 4 GATE-PLANES:
//         idx(g,t,blk2,wj,L) = (((g*TC+t)*64 + blk2)*512) + wj*64 + L
//         where blk2=batch>>2, j=gate&127, wj=j>>4, L=(j&15)*4+(batch&3).
//       Epilogue: 16x 8-B contiguous dwordx2 stores/thread (was 64x 2-B scatter).
//   lstm_mfma_kernel : 64 blocks (RB=4) x 512 thr (8 waves), lane-spread
//       activations (1 unit/thread). W_hh static in VGPRs, h double-buffered in
//       LDS. ROUND 8: HROW=144 (72 dwords = 8 mod 32 -> Bf b128 reads uniform
//       2-way = conflict-free; HROW=136 caused 4-way conflicts). gx = 4 coalesced
//       ushort loads/lane/step (one per gate plane), depth-4 prefetch ring.
//   head_kernel : tiny MLP per row.

#define TC       128
#define NCHUNK   4
#define BATCH    256
#define TSEQ     512
#define ISZ      256
#define HSZ      128
#define G4       512
#define RB       4
#define NBLK     (BATCH / RB)
#define HROW     144              // shorts; 72 dwords = 8 mod 32 -> 2-way only
#define GX_PER_T 131072           // gx elements per timestep (all 4 planes)
#define STRT     32768            // per-plane step stride in shorts (64*512)
#define PF       4                // gx prefetch depth in steps

typedef __attribute__((ext_vector_type(8))) short short8;
typedef __attribute__((ext_vector_type(4))) short shortx4;
typedef __attribute__((ext_vector_type(4))) float f32x4;

__device__ __forceinline__ void barrier_nodrain() {
    // s_barrier WITHOUT the compiler's vmcnt(0) drain: LDS consistency only.
    __asm__ __volatile__("s_waitcnt lgkmcnt(0)\n\ts_barrier" ::: "memory");
}
__device__ __forceinline__ void lds_fence() {
    // order this wave's LDS write->read (exchange buffer is wave-private)
    __asm__ __volatile__("s_waitcnt lgkmcnt(0)" ::: "memory");
}

__device__ __forceinline__ float fast_rcp(float x) {
    return __builtin_amdgcn_rcpf(x);
}
__device__ __forceinline__ float sigmoidf_(float x) {
    return fast_rcp(1.0f + __expf(-x));
}
__device__ __forceinline__ float tanhf_(float x) {
    float e = __expf(2.0f * x);               // inf-safe
    return 1.0f - 2.0f * fast_rcp(e + 1.0f);
}
__device__ __forceinline__ unsigned short f2bf(float x) {  // fp32 -> bf16 RNE
    union { float f; unsigned u; } v; v.f = x;
    unsigned r = v.u + 0x7fffu + ((v.u >> 16) & 1u);
    return (unsigned short)(r >> 16);
}
__device__ __forceinline__ float bf2f(unsigned short b) {
    union { unsigned u; float f; } v;
    v.u = ((unsigned)b) << 16;
    return v.f;
}
__device__ __forceinline__ unsigned packbf(float lo, float hi) {  // packed HW cvt
    __hip_bfloat162 h2 = __float22bfloat162_rn(make_float2(lo, hi));
    union { __hip_bfloat162 h; unsigned u; } v; v.h = h2;
    return v.u;
}

// ---------------------------------------------------------------------------
// bf16 MFMA GEMM: per chunk M = TC*256 (m=(tl,batch)), N = 128 j for plane nt,
// K = 256. Double-buffered LDS, 1 barrier/slice.
__global__ __launch_bounds__(256, 2) void gemm_gx_kernel(
    const float* __restrict__ x, const float* __restrict__ Wih,
    const float* __restrict__ bih, const float* __restrict__ bhh,
    unsigned short* __restrict__ gxb, int t0)
{
    __shared__ __align__(16) short As[2][128 * 32];
    __shared__ __align__(16) short Bs[2][128 * 32];
    const int tid = threadIdx.x;
    const int mt  = blockIdx.x;
    const int nt  = blockIdx.y;            // gate plane g
    const int tl  = mt >> 1;
    const int b0  = (mt & 1) * 128;
    const int n0  = nt * 128;

    const int w    = tid >> 6;
    const int lane = tid & 63;
    const int n    = lane & 15;
    const int quad = lane >> 4;
    const int mq   = w & 1;
    const int nq   = w >> 1;

    const int srow = tid >> 1;
    const int skh  = (tid & 1) * 16;
    const float* xrow = x + ((size_t)(b0 + srow) * TSEQ + (size_t)(t0 + tl)) * ISZ + skh;
    const float* wrow = Wih + (size_t)(n0 + srow) * ISZ + skh;

    f32x4 acc[4][4];
#pragma unroll
    for (int mi = 0; mi < 4; ++mi)
#pragma unroll
        for (int ni = 0; ni < 4; ++ni)
            acc[mi][ni] = (f32x4){0.f, 0.f, 0.f, 0.f};

    {
        float4 pa[4], pb[4];
#pragma unroll
        for (int j = 0; j < 4; ++j) {
            pa[j] = *(const float4*)(xrow + j * 4);
            pb[j] = *(const float4*)(wrow + j * 4);
        }
        unsigned ua[8], ub[8];
#pragma unroll
        for (int j = 0; j < 4; ++j) {
            ua[2 * j]     = packbf(pa[j].x, pa[j].y);
            ua[2 * j + 1] = packbf(pa[j].z, pa[j].w);
            ub[2 * j]     = packbf(pb[j].x, pb[j].y);
            ub[2 * j + 1] = packbf(pb[j].z, pb[j].w);
        }
        *(uint4*)(&As[0][srow * 32 + skh])     = (uint4){ua[0], ua[1], ua[2], ua[3]};
        *(uint4*)(&As[0][srow * 32 + skh + 8]) = (uint4){ua[4], ua[5], ua[6], ua[7]};
        *(uint4*)(&Bs[0][srow * 32 + skh])     = (uint4){ub[0], ub[1], ub[2], ub[3]};
        *(uint4*)(&Bs[0][srow * 32 + skh + 8]) = (uint4){ub[4], ub[5], ub[6], ub[7]};
    }
    barrier_nodrain();

    for (int ks = 0; ks < 8; ++ks) {
        const int cur = ks & 1;
        const int nxt = cur ^ 1;

        float4 pa[4], pb[4];
        if (ks < 7) {
#pragma unroll
            for (int j = 0; j < 4; ++j) {
                pa[j] = *(const float4*)(xrow + (ks + 1) * 32 + j * 4);
                pb[j] = *(const float4*)(wrow + (ks + 1) * 32 + j * 4);
            }
        }

        short8 af[4], bf[4];
#pragma unroll
        for (int mi = 0; mi < 4; ++mi)
            af[mi] = *(const short8*)(&As[cur][((mq * 4 + mi) * 16 + n) * 32 + quad * 8]);
#pragma unroll
        for (int ni = 0; ni < 4; ++ni)
            bf[ni] = *(const short8*)(&Bs[cur][((nq * 4 + ni) * 16 + n) * 32 + quad * 8]);
#pragma unroll
        for (int mi = 0; mi < 4; ++mi)
#pragma unroll
            for (int ni = 0; ni < 4; ++ni)
                acc[mi][ni] = __builtin_amdgcn_mfma_f32_16x16x32_bf16(
                    af[mi], bf[ni], acc[mi][ni], 0, 0, 0);

        if (ks < 7) {
            unsigned ua[8], ub[8];
#pragma unroll
            for (int j = 0; j < 4; ++j) {
                ua[2 * j]     = packbf(pa[j].x, pa[j].y);
                ua[2 * j + 1] = packbf(pa[j].z, pa[j].w);
                ub[2 * j]     = packbf(pb[j].x, pb[j].y);
                ub[2 * j + 1] = packbf(pb[j].z, pb[j].w);
            }
            *(uint4*)(&As[nxt][srow * 32 + skh])     = (uint4){ua[0], ua[1], ua[2], ua[3]};
            *(uint4*)(&As[nxt][srow * 32 + skh + 8]) = (uint4){ua[4], ua[5], ua[6], ua[7]};
            *(uint4*)(&Bs[nxt][srow * 32 + skh])     = (uint4){ub[0], ub[1], ub[2], ub[3]};
            *(uint4*)(&Bs[nxt][srow * 32 + skh + 8]) = (uint4){ub[4], ub[5], ub[6], ub[7]};
        }
        barrier_nodrain();
    }

    // epilogue: bias + bf16, gate-plane layout, 8-B contiguous stores.
    // j = nq*64 + ni*16 + n -> wj = nq*4+ni, j&15 = n; L = n*4 + (batch&3).
#pragma unroll
    for (int ni = 0; ni < 4; ++ni) {
        const int j    = nq * 64 + ni * 16 + n;
        const int gate = n0 + j;
        const float bias = bih[gate] + bhh[gate];
        const int wj = nq * 4 + ni;
#pragma unroll
        for (int mi = 0; mi < 4; ++mi) {
            const int bb   = b0 + mq * 64 + mi * 16 + quad * 4;   // mult of 4
            const int blk2 = bb >> 2;
            const size_t idx = ((((size_t)nt * TC + tl) * 64 + blk2) * 512) +
                               (size_t)wj * 64 + (size_t)n * 4;
            const unsigned lo = packbf(acc[mi][ni][0] + bias, acc[mi][ni][1] + bias);
            const unsigned hi = packbf(acc[mi][ni][2] + bias, acc[mi][ni][3] + bias);
            *(uint2*)(&gxb[idx]) = (uint2){lo, hi};
        }
    }
}

// ---------------------------------------------------------------------------
// MFMA recurrence, lane-spread activations.
// 64 blocks x 512 thr (8 waves), RB=4 batch rows per block (blk2 == blockIdx.x).
// Wave w: gate-tiles {w,8+w,16+w,24+w}, j in [16w,16w+16), D cols 0..3 real.
// Unit mapping: lane L -> (j = 16w + (L>>2), b = L&3); c held in-lane.
__global__ __launch_bounds__(512, 2) void lstm_mfma_kernel(
    const unsigned short* __restrict__ gxb, const float* __restrict__ Whh,
    float* __restrict__ hc, int first)
{
    __shared__ __align__(16) short h_lds[2 * RB * HROW];   // double-buffered h (bf16)
    __shared__ __align__(16) float ex_lds[8 * 256];        // per-wave exchange [g][b][j]
    const int blk  = blockIdx.x;
    const int b0   = blk * RB;
    const int tid  = threadIdx.x;
    const int w    = tid >> 6;
    const int lane = tid & 63;
    const int n    = lane & 15;
    const int quad = lane >> 4;
    const int nb   = lane & 3;           // B-frag row (clamped) == unit batch
    const int jl   = lane >> 2;          // unit j-local 0..15
    const int j    = 16 * w + jl;        // unit hidden index
    float* exw = ex_lds + w * 256;

    // static A-frags: W_hh[128g + 16w + n][32ks + 8quad + i] as bf16
    short8 Af[4][4];
#pragma unroll
    for (int g = 0; g < 4; ++g) {
        const float* row = Whh + (size_t)(128 * g + 16 * w + n) * HSZ + 8 * quad;
#pragma unroll
        for (int ks = 0; ks < 4; ++ks)
#pragma unroll
            for (int i = 0; i < 8; ++i)
                Af[g][ks][i] = (short)f2bf(row[32 * ks + i]);
    }

    // init unit state: every thread owns one (j, b) unit
    float c1 = 0.f, hl1 = 0.f;
    {
        unsigned short h0 = 0;
        if (!first) {
            c1 = hc[(size_t)BATCH * HSZ + (size_t)(b0 + nb) * HSZ + j];
            h0 = f2bf(hc[(size_t)(b0 + nb) * HSZ + j]);
        }
        *(unsigned short*)&h_lds[nb * HROW + j] = h0;   // buffer 0
    }

    // gx: 4 coalesced ushort loads per lane per step (one per gate plane)
    const unsigned short* gp[4];
#pragma unroll
    for (int g = 0; g < 4; ++g)
        gp[g] = gxb + (((size_t)g * TC) * 64 + blk) * 512 + (size_t)w * 64 + lane;

    unsigned short gq[PF][4];
#pragma unroll
    for (int d = 0; d < PF; ++d)
#pragma unroll
        for (int g = 0; g < 4; ++g)
            gq[d][g] = gp[g][(size_t)d * STRT];

    barrier_nodrain();

    for (int t = 0; t < TC; t += PF) {
#pragma unroll
        for (int u = 0; u < PF; ++u) {
            const int tt = t + u;
            const short* hb_r = h_lds + (u & 1) * (RB * HROW);
            short*       hb_w = h_lds + ((u & 1) ^ 1) * (RB * HROW);

            short8 Bf[4];
#pragma unroll
            for (int ks = 0; ks < 4; ++ks)
                Bf[ks] = *(const short8*)(&hb_r[nb * HROW + 32 * ks + 8 * quad]);

            // refill prefetch slot u for step tt+PF (clamped; value unused at end)
            const int tf = (tt + PF < TC) ? (tt + PF) : (TC - 1);
            unsigned short gnew[4];
#pragma unroll
            for (int g = 0; g < 4; ++g)
                gnew[g] = gp[g][(size_t)tf * STRT];

            // MFMAs: zero-C first, 4 independent chains
            f32x4 acc[4];
#pragma unroll
            for (int g = 0; g < 4; ++g)
                acc[g] = __builtin_amdgcn_mfma_f32_16x16x32_bf16(
                    Af[g][0], Bf[0], (f32x4){0.f, 0.f, 0.f, 0.f}, 0, 0, 0);
#pragma unroll
            for (int ks = 1; ks < 4; ++ks)
#pragma unroll
                for (int g = 0; g < 4; ++g)
                    acc[g] = __builtin_amdgcn_mfma_f32_16x16x32_bf16(
                        Af[g][ks], Bf[ks], acc[g], 0, 0, 0);

            // exchange: real cols (n<4) -> wave-private LDS, [g][b][j] fp32
            if (n < 4) {
#pragma unroll
                for (int g = 0; g < 4; ++g)
                    *(f32x4*)(&exw[(g * 4 + n) * 16 + 4 * quad]) = acc[g];
            }
            lds_fence();   // wave-internal write->read ordering

            const float d0 = exw[(0 * 4 + nb) * 16 + jl];
            const float d1 = exw[(1 * 4 + nb) * 16 + jl];
            const float d2 = exw[(2 * 4 + nb) * 16 + jl];
            const float d3 = exw[(3 * 4 + nb) * 16 + jl];

            const float ig = sigmoidf_(d0 + bf2f(gq[u][0]));
            const float fg = sigmoidf_(d1 + bf2f(gq[u][1]));
            const float gg = tanhf_(d2 + bf2f(gq[u][2]));
            const float og = sigmoidf_(d3 + bf2f(gq[u][3]));
            c1  = fg * c1 + ig * gg;
            hl1 = og * tanhf_(c1);
#pragma unroll
            for (int g = 0; g < 4; ++g) gq[u][g] = gnew[g];

            *(unsigned short*)&hb_w[nb * HROW + j] = f2bf(hl1);
            barrier_nodrain();
        }
    }

    hc[(size_t)(b0 + nb) * HSZ + j] = hl1;
    hc[(size_t)BATCH * HSZ + (size_t)(b0 + nb) * HSZ + j] = c1;
}

// ---------------------------------------------------------------------------
// MLP head: one block (64 threads) per batch row.
__global__ __launch_bounds__(64) void head_kernel(
    const float* __restrict__ hc,
    const float* __restrict__ W1, const float* __restrict__ b1,
    const float* __restrict__ W2, const float* __restrict__ b2,
    const float* __restrict__ W3, const float* __restrict__ b3,
    float* __restrict__ out)
{
    __shared__ float hs[HSZ];
    __shared__ float o1[64];
    __shared__ float o2[32];
    const int bidx = blockIdx.x;
    const int t = threadIdx.x;
    hs[t]      = hc[bidx * HSZ + t];
    hs[t + 64] = hc[bidx * HSZ + t + 64];
    __syncthreads();
    {
        float a = b1[t];
#pragma unroll 8
        for (int k = 0; k < HSZ; ++k) a += W1[t * HSZ + k] * hs[k];
        o1[t] = fmaxf(a, 0.0f);
    }
    __syncthreads();
    if (t < 32) {
        float a = b2[t];
#pragma unroll 8
        for (int k = 0; k < 64; ++k) a += W2[t * 64 + k] * o1[k];
        o2[t] = fmaxf(a, 0.0f);
    }
    __syncthreads();
    if (t < 4) {
        float a = b3[t];
#pragma unroll
        for (int k = 0; k < 32; ++k) a += W3[t * 32 + k] * o2[k];
        out[bidx * 4 + t] = a;
    }
}

// ---------------------------------------------------------------------------
extern "C" void kernel_launch(void* const* d_in, const int* in_sizes, int n_in,
                              void* d_out, int out_size, void* d_ws, size_t ws_size,
                              hipStream_t stream) {
    const float* x   = (const float*)d_in[0];
    const float* Wih = (const float*)d_in[1];
    const float* Whh = (const float*)d_in[2];
    const float* bih = (const float*)d_in[3];
    const float* bhh = (const float*)d_in[4];
    const float* W1  = (const float*)d_in[5];
    const float* b1  = (const float*)d_in[6];
    const float* W2  = (const float*)d_in[7];
    const float* b2  = (const float*)d_in[8];
    const float* W3  = (const float*)d_in[9];
    const float* b3  = (const float*)d_in[10];
    float* out = (float*)d_out;

    unsigned short* gxb = (unsigned short*)d_ws;                   // 33.55 MB bf16
    float* hc = (float*)((char*)d_ws + (size_t)TC * GX_PER_T * 2); // 256 KB h+c

    for (int c = 0; c < NCHUNK; ++c) {
        gemm_gx_kernel<<<dim3(2 * TC, 4), 256, 0, stream>>>(x, Wih, bih, bhh, gxb, c * TC);
        lstm_mfma_kernel<<<dim3(NBLK), 512, 0, stream>>>(gxb, Whh, hc, c == 0);
    }
    head_kernel<<<dim3(BATCH), 64, 0, stream>>>(hc, W1, b1, W2, b2, W3, b3, out);
}